// Round 9
// baseline (132.704 us; speedup 1.0000x reference)
//
#include <hip/hip_runtime.h>
#include <math.h>

#define B_DIM 1024
#define D_DIM 512
#define H_DIM 128
#define S_DIM 511
#define PI_F 3.14159265358979323846f
#define ZSWZ_BYTES (8u * 1024u * 128u)      /* 1 MiB: z bf16, fragment-ordered */
#define NTILES_TOTAL 2296                    /* sum over s of ceil((s+1)/64) */
#define W1BF_BYTES ((size_t)NTILES_TOTAL * 16384)

typedef __attribute__((ext_vector_type(8))) short short8;
typedef __attribute__((ext_vector_type(4))) float f32x4;

static __device__ __forceinline__ unsigned cvt_pk_bf16(float lo, float hi) {
    unsigned r;
    asm("v_cvt_pk_bf16_f32 %0, %1, %2" : "=v"(r) : "v"(lo), "v"(hi));
    return r;
}

// 64-wide k-tiles before site s in the packed W1bf buffer
static __device__ __forceinline__ int tiles_before(int s) {
    const int q = s >> 6, r = s & 63;
    return s + 32 * q * (q - 1) + q * r;
}

// Fragment-ordered tile layout (16 KB per 128x64 bf16 tile):
//   chunk(row r 0..127, k-granule g 0..7 [8 bf16]) at byte
//   ((r>>4)*2 + (g>>2))*1024 + (g&3)*256 + (r&15)*16
// => wave frag load for (rowblock R=r>>4, ks=g>>2) = base + (R*2+ks)*1024 + lane*16
//    (lane = l16*16+l15 -> l16*256 + l15*16)  — one contiguous 1KB per load.

// ---------------------------------------------------------------------------
// Pack kernel. Blocks [0,256): z f32 -> bf16 fragment-ordered tiles
// [bblk 0..7][ktile 0..7]. Blocks [256,...): W1 f32 [k][h] -> bf16 [h][k]
// fragment-ordered 16KB tiles (BK=64), triangular-packed, K-mask baked in.
// ---------------------------------------------------------------------------
__global__ __launch_bounds__(256) void pack_kernel(
        const float* __restrict__ z, const float* __restrict__ W1,
        unsigned char* __restrict__ z_frag, unsigned char* __restrict__ w1bf)
{
    if (blockIdx.x < 256) {
        const int gid = blockIdx.x * 256 + threadIdx.x;   // 65536 threads
        const int g   = gid & 7;                          // k-granule
        const int row = (gid >> 3) & 1023;
        const int kt  = gid >> 13;                        // ktile 0..7
        const float* src = z + (size_t)row * D_DIM + kt * 64 + g * 8;
        float4 a = *(const float4*)src;
        float4 b = *(const float4*)(src + 4);
        uint4 w;
        w.x = cvt_pk_bf16(a.x, a.y);
        w.y = cvt_pk_bf16(a.z, a.w);
        w.z = cvt_pk_bf16(b.x, b.y);
        w.w = cvt_pk_bf16(b.z, b.w);
        const int r7 = row & 127;
        const int tile = (row >> 7) * 8 + kt;
        const int off = (((r7 >> 4) * 2 + (g >> 2)) << 10) + ((g & 3) << 8) + ((r7 & 15) << 4);
        *(uint4*)(z_frag + (size_t)tile * 16384 + off) = w;
        return;
    }
    const int tb = blockIdx.x - 256;          // 0..4087
    const int s  = tb >> 3;
    const int kk = tb & 7;
    if (s >= S_DIM || kk > (s >> 6)) return;
    const int k0 = kk << 6;
    const int t  = threadIdx.x;
    const int h2 = t & 63;                    // h pair: h0=2*h2, h1
    const int mw = t >> 6;                    // granules m = mw, mw+4
    const float* __restrict__ W1s = W1 + (size_t)s * (D_DIM * H_DIM);
    unsigned char* out = w1bf + (size_t)(tiles_before(s) + kk) * 16384;
    const int h0 = h2 * 2, h1 = h2 * 2 + 1;
#pragma unroll
    for (int half = 0; half < 2; ++half) {
        const int m = mw + half * 4;          // k-granule 0..7
        float2 v[8];
#pragma unroll
        for (int e = 0; e < 8; ++e) {
            const int gk = k0 + m * 8 + e;
            v[e] = (gk <= s) ? *(const float2*)(W1s + (size_t)gk * H_DIM + h0)
                             : (float2){0.f, 0.f};
        }
        uint4 w0, w1;
        w0.x = cvt_pk_bf16(v[0].x, v[1].x); w0.y = cvt_pk_bf16(v[2].x, v[3].x);
        w0.z = cvt_pk_bf16(v[4].x, v[5].x); w0.w = cvt_pk_bf16(v[6].x, v[7].x);
        w1.x = cvt_pk_bf16(v[0].y, v[1].y); w1.y = cvt_pk_bf16(v[2].y, v[3].y);
        w1.z = cvt_pk_bf16(v[4].y, v[5].y); w1.w = cvt_pk_bf16(v[6].y, v[7].y);
        const int base0 = (((h0 >> 4) * 2 + (m >> 2)) << 10) + ((m & 3) << 8);
        *(uint4*)(out + base0 + ((h0 & 15) << 4)) = w0;
        *(uint4*)(out + base0 + ((h1 & 15) << 4)) = w1;
    }
}

// ---------------------------------------------------------------------------
// Chained site kernel (PRE=true): NO LDS, NO barriers in the K-loop.
// Both operands stream L2 -> registers as wave-contiguous 1KB dwordx4 loads
// (fragment-ordered scratch), register double-buffered; the compiler's
// register-dependency vmcnt provides counted waits automatically. 512 blocks
// = 64 chains x 8 bblocks; chain c's bblocks share XCD c&7 for W1 L2 reuse.
// ---------------------------------------------------------------------------
template<bool PRE>
__global__ __launch_bounds__(256) void ar_site_kernel(
        const float* __restrict__ z, const unsigned char* __restrict__ z_frag,
        const unsigned char* __restrict__ w1bf,
        const float* __restrict__ W1, const float* __restrict__ b1,
        const float* __restrict__ W2, const float* __restrict__ b2,
        float* __restrict__ x_out, float* __restrict__ ld_out)
{
    __shared__ __align__(16) unsigned char lds[36864];  // fallback stage + epi

    const int tid  = threadIdx.x;
    const int lane = tid & 63;
    const int wid  = tid >> 6;
    const int wr   = wid >> 1;
    const int wc   = wid & 1;
    const int l15  = lane & 15;
    const int l16  = lane >> 4;

    if (PRE) {
        const int epi = 0;                       // epi scratch at lds[0..4K)
        const int ib   = blockIdx.x;             // 0..511
        const int c    = (((ib >> 3) & 7) << 3) | (ib & 7);  // chain 0..63
        const int bblk = ib >> 6;                // 0..7
        const int brow0 = bblk * 128;

        // ---- prefetch stream state over (t, kk) of this chain (block-uniform)
        int pf_t = 0, pf_kk = 0;
        int pf_s = 510 - c;
        int pf_base = tiles_before(pf_s);

        short8 A0[8], B0[8], A1[8], B1[8];

        // issue 16 frag loads for the pf-current step into (NA, NB), advance pf
#define STEP_LOAD(NA, NB)                                                       \
        if (pf_t < 8) {                                                         \
            const unsigned char* ab = z_frag + (((size_t)(bblk * 8 + pf_kk)) << 14) \
                                      + (wr * 8 << 10) + lane * 16;             \
            const unsigned char* bb = w1bf + (((size_t)(pf_base + pf_kk)) << 14)    \
                                      + (wc * 8 << 10) + lane * 16;             \
            _Pragma("unroll")                                                   \
            for (int i = 0; i < 8; ++i) {                                       \
                NA[i] = *(const short8*)(ab + i * 1024);                        \
                NB[i] = *(const short8*)(bb + i * 1024);                        \
            }                                                                   \
            ++pf_kk;                                                            \
            if (pf_kk == ((pf_s >> 6) + 1)) {                                   \
                pf_kk = 0; ++pf_t;                                              \
                while (pf_t < 8) {                                              \
                    const int jj = pf_t * 64 + ((pf_t & 1) ? (63 - c) : c);     \
                    if (jj < S_DIM) { pf_s = 510 - jj; pf_base = tiles_before(pf_s); break; } \
                    ++pf_t;                                                     \
                }                                                               \
            }                                                                   \
        }

#define STEP_MFMA(CA, CB)                                                       \
        __builtin_amdgcn_s_setprio(1);                                          \
        _Pragma("unroll")                                                       \
        for (int ks = 0; ks < 2; ++ks)                                          \
            _Pragma("unroll")                                                   \
            for (int mi = 0; mi < 4; ++mi)                                      \
                _Pragma("unroll")                                               \
                for (int ni = 0; ni < 4; ++ni)                                  \
                    acc[mi][ni] = __builtin_amdgcn_mfma_f32_16x16x32_bf16(      \
                        CA[mi * 2 + ks], CB[ni * 2 + ks], acc[mi][ni], 0, 0, 0);\
        __builtin_amdgcn_s_setprio(0);

        STEP_LOAD(A0, B0);                   // prologue: step 0 -> buffer 0
        int parity = 0;
        float ld_acc = 0.f;

        for (int t = 0; t < 8; ++t) {
            const int j = t * 64 + ((t & 1) ? (63 - c) : c);
            if (j >= S_DIM) continue;
            const int s   = 510 - j;
            const int nt  = (s >> 6) + 1;
            const int idx = s + 1;

            f32x4 acc[4][4];
#pragma unroll
            for (int mi = 0; mi < 4; ++mi)
#pragma unroll
                for (int ni = 0; ni < 4; ++ni)
                    acc[mi][ni] = (f32x4){0.f, 0.f, 0.f, 0.f};

            for (int kk = 0; kk < nt; ++kk) {
                if (parity == 0) {
                    STEP_LOAD(A1, B1);       // loads fly during MFMA below
                    STEP_MFMA(A0, B0);
                    parity = 1;
                } else {
                    STEP_LOAD(A0, B0);
                    STEP_MFMA(A1, B1);
                    parity = 0;
                }
            }

            // ---- site epilogue: p = relu(acc+b1) @ W2, then NCP transform
            float b1v[4], w2a[4], w2b[4];
#pragma unroll
            for (int ni = 0; ni < 4; ++ni) {
                const int cc = wc * 64 + ni * 16 + l15;
                b1v[ni] = b1[(size_t)s * H_DIM + cc];
                const float2 w2v = *(const float2*)(W2 + ((size_t)s * H_DIM + cc) * 2);
                w2a[ni] = w2v.x;
                w2b[ni] = w2v.y;
            }
            float p0s[4][4], p1s[4][4];
#pragma unroll
            for (int mi = 0; mi < 4; ++mi)
#pragma unroll
                for (int r = 0; r < 4; ++r) {
                    float p0 = 0.f, p1 = 0.f;
#pragma unroll
                    for (int ni = 0; ni < 4; ++ni) {
                        float h = fmaxf(acc[mi][ni][r] + b1v[ni], 0.f);
                        p0 = fmaf(h, w2a[ni], p0);
                        p1 = fmaf(h, w2b[ni], p1);
                    }
                    p0s[mi][r] = p0; p1s[mi][r] = p1;
                }
#pragma unroll
            for (int mi = 0; mi < 4; ++mi)
#pragma unroll
                for (int r = 0; r < 4; ++r) {
                    p0s[mi][r] += __shfl_xor(p0s[mi][r], 1);
                    p0s[mi][r] += __shfl_xor(p0s[mi][r], 2);
                    p1s[mi][r] += __shfl_xor(p1s[mi][r], 1);
                    p1s[mi][r] += __shfl_xor(p1s[mi][r], 2);
                }
            if ((lane & 3) == 0) {
                const int cw = wc * 4 + (l15 >> 2);
#pragma unroll
                for (int mi = 0; mi < 4; ++mi)
#pragma unroll
                    for (int r = 0; r < 4; ++r) {
                        const int row = wr * 64 + mi * 16 + l16 * 4 + r;
                        *(float2*)(lds + epi + (row * 8 + (cw ^ (row & 7))) * 8)
                            = (float2){p0s[mi][r], p1s[mi][r]};
                    }
            }
            __syncthreads();
            if (tid < 128) {
                const int row = tid;
                float alpha = b2[(size_t)s * 2 + 0];
                float beta  = b2[(size_t)s * 2 + 1];
#pragma unroll
                for (int cw = 0; cw < 8; ++cw) {
                    const float2 v = *(const float2*)(lds + epi + (row * 8 + (cw ^ (row & 7))) * 8);
                    alpha += v.x; beta += v.y;
                }
                const int grow = brow0 + row;
                const float phi = z[(size_t)grow * D_DIM + idx];
                const float u = tanf(0.5f * (phi - PI_F));
                const float a = expf(alpha);
                const float v = fmaf(a, u, beta);
                x_out[(size_t)grow * D_DIM + idx] = 2.0f * atanf(v) + PI_F;
                ld_acc += alpha + log1pf(u * u) - log1pf(v * v);
            }
            __syncthreads();   // epi buffer reusable next site
        }
        if (tid < 128) atomicAdd(ld_out + brow0 + tid, ld_acc);
        if (c == 0 && tid < 128)
            x_out[(size_t)(brow0 + tid) * D_DIM] = z[(size_t)(brow0 + tid) * D_DIM];
        return;
#undef STEP_LOAD
#undef STEP_MFMA
    }

    // ---------------- legacy fallback: one site per block, in-kernel cvt ----
    const int EPI2 = 32768;
    const int ib    = blockIdx.x;
    const int s_idx = ((ib >> 6) << 3) | (ib & 7);
    if (s_idx >= S_DIM) return;
    const int s     = S_DIM - 1 - s_idx;
    const int bblk  = (ib >> 3) & 7;
    const int brow0 = bblk * 128;
    const int K     = s + 1;
    const int idx   = s + 1;
    const float* __restrict__ W1s = W1 + (size_t)s * (D_DIM * H_DIM);

    f32x4 acc[4][4];
#pragma unroll
    for (int mi = 0; mi < 4; ++mi)
#pragma unroll
        for (int ni = 0; ni < 4; ++ni)
            acc[mi][ni] = (f32x4){0.f, 0.f, 0.f, 0.f};

    const int ntiles = (K + 63) >> 6;
    for (int kk = 0; kk < ntiles; ++kk) {
        const int k0 = kk << 6;
        const int g  = tid & 7;
        const int rb = tid >> 3;
#pragma unroll
        for (int p = 0; p < 4; ++p) {
            const int row  = p * 32 + rb;
            const int srcg = g ^ (row & 7);
            const float* zp = z + (size_t)(brow0 + row) * D_DIM + k0 + srcg * 8;
            float4 va = *(const float4*)zp;
            float4 vb = *(const float4*)(zp + 4);
            uint4 w;
            w.x = cvt_pk_bf16(va.x, va.y);
            w.y = cvt_pk_bf16(va.z, va.w);
            w.z = cvt_pk_bf16(vb.x, vb.y);
            w.w = cvt_pk_bf16(vb.z, vb.w);
            *(uint4*)(lds + row * 128 + g * 16) = w;
        }
        const int hgrp  = tid & 31;
        const int kgrp  = tid >> 5;
        const int kbase = k0 + kgrp * 8;
        const float* wp = W1s + (size_t)kbase * H_DIM + hgrp * 4;
        float4 cc[8];
#pragma unroll
        for (int jj = 0; jj < 8; ++jj) {
            float4 v = *(const float4*)(wp + (size_t)jj * H_DIM);
            const bool ok = (kbase + jj) < K;
            v.x = ok ? v.x : 0.f;  v.y = ok ? v.y : 0.f;
            v.z = ok ? v.z : 0.f;  v.w = ok ? v.w : 0.f;
            cc[jj] = v;
        }
        const float* cf = (const float*)cc;
#pragma unroll
        for (int i2 = 0; i2 < 4; ++i2) {
            const int h = hgrp * 4 + i2;
            uint4 w;
            w.x = cvt_pk_bf16(cf[0 * 4 + i2], cf[1 * 4 + i2]);
            w.y = cvt_pk_bf16(cf[2 * 4 + i2], cf[3 * 4 + i2]);
            w.z = cvt_pk_bf16(cf[4 * 4 + i2], cf[5 * 4 + i2]);
            w.w = cvt_pk_bf16(cf[6 * 4 + i2], cf[7 * 4 + i2]);
            *(uint4*)(lds + 16384 + h * 128 + ((kgrp * 16) ^ ((h & 7) << 4))) = w;
        }
        __syncthreads();
#pragma unroll
        for (int ks = 0; ks < 2; ++ks) {
            const int kb = ks * 64 + l16 * 16;
            short8 af[4], bfr[4];
#pragma unroll
            for (int mi = 0; mi < 4; ++mi) {
                const int r = wr * 64 + mi * 16 + l15;
                af[mi] = *(const short8*)(lds + r * 128 + (kb ^ ((r & 7) << 4)));
            }
#pragma unroll
            for (int ni = 0; ni < 4; ++ni) {
                const int h = wc * 64 + ni * 16 + l15;
                bfr[ni] = *(const short8*)(lds + 16384 + h * 128 + (kb ^ ((h & 7) << 4)));
            }
#pragma unroll
            for (int mi = 0; mi < 4; ++mi)
#pragma unroll
                for (int ni = 0; ni < 4; ++ni)
                    acc[mi][ni] = __builtin_amdgcn_mfma_f32_16x16x32_bf16(
                        af[mi], bfr[ni], acc[mi][ni], 0, 0, 0);
        }
        __syncthreads();
    }

    float b1v[4], w2a[4], w2b[4];
#pragma unroll
    for (int ni = 0; ni < 4; ++ni) {
        const int cc2 = wc * 64 + ni * 16 + l15;
        b1v[ni] = b1[(size_t)s * H_DIM + cc2];
        const float* w2p = W2 + ((size_t)s * H_DIM + cc2) * 2;
        w2a[ni] = w2p[0];
        w2b[ni] = w2p[1];
    }
    float p0s[4][4], p1s[4][4];
#pragma unroll
    for (int mi = 0; mi < 4; ++mi)
#pragma unroll
        for (int r = 0; r < 4; ++r) {
            float p0 = 0.f, p1 = 0.f;
#pragma unroll
            for (int ni = 0; ni < 4; ++ni) {
                float h = fmaxf(acc[mi][ni][r] + b1v[ni], 0.f);
                p0 = fmaf(h, w2a[ni], p0);
                p1 = fmaf(h, w2b[ni], p1);
            }
            p0s[mi][r] = p0; p1s[mi][r] = p1;
        }
#pragma unroll
    for (int mi = 0; mi < 4; ++mi)
#pragma unroll
        for (int r = 0; r < 4; ++r) {
            p0s[mi][r] += __shfl_xor(p0s[mi][r], 1);
            p0s[mi][r] += __shfl_xor(p0s[mi][r], 2);
            p1s[mi][r] += __shfl_xor(p1s[mi][r], 1);
            p1s[mi][r] += __shfl_xor(p1s[mi][r], 2);
        }
    if ((lane & 3) == 0) {
        const int cw = wc * 4 + (l15 >> 2);
#pragma unroll
        for (int mi = 0; mi < 4; ++mi)
#pragma unroll
            for (int r = 0; r < 4; ++r) {
                const int row = wr * 64 + mi * 16 + l16 * 4 + r;
                *(float2*)(lds + EPI2 + (row * 8 + (cw ^ (row & 7))) * 8)
                    = (float2){p0s[mi][r], p1s[mi][r]};
            }
    }
    __syncthreads();
    if (tid < 128) {
        const int row = tid;
        float alpha = b2[(size_t)s * 2 + 0];
        float beta  = b2[(size_t)s * 2 + 1];
#pragma unroll
        for (int cw = 0; cw < 8; ++cw) {
            const float2 v = *(const float2*)(lds + EPI2 + (row * 8 + (cw ^ (row & 7))) * 8);
            alpha += v.x; beta += v.y;
        }
        const int grow = brow0 + row;
        const float phi = z[(size_t)grow * D_DIM + idx];
        const float u = tanf(0.5f * (phi - PI_F));
        const float a = expf(alpha);
        const float v = fmaf(a, u, beta);
        x_out[(size_t)grow * D_DIM + idx] = 2.0f * atanf(v) + PI_F;
        atomicAdd(ld_out + grow, alpha + log1pf(u * u) - log1pf(v * v));
        if (s_idx == 0)
            x_out[(size_t)grow * D_DIM] = z[(size_t)grow * D_DIM];
    }
}

extern "C" void kernel_launch(void* const* d_in, const int* in_sizes, int n_in,
                              void* d_out, int out_size, void* d_ws, size_t ws_size,
                              hipStream_t stream) {
    const float* z  = (const float*)d_in[0];
    const float* W1 = (const float*)d_in[1];
    const float* b1 = (const float*)d_in[2];
    const float* W2 = (const float*)d_in[3];
    const float* b2 = (const float*)d_in[4];
    float* x_out  = (float*)d_out;
    float* ld_out = x_out + (size_t)B_DIM * D_DIM;

    unsigned char* z_frag = (unsigned char*)d_ws;
    unsigned char* w1bf   = z_frag + ZSWZ_BYTES;
    const size_t need = ZSWZ_BYTES + W1BF_BYTES;

    hipMemsetAsync(ld_out, 0, B_DIM * sizeof(float), stream);
    if (ws_size >= need) {
        pack_kernel<<<dim3(256 + 4088), dim3(256), 0, stream>>>(z, W1, z_frag, w1bf);
        ar_site_kernel<true><<<dim3(512), dim3(256), 0, stream>>>(
            z, z_frag, w1bf, W1, b1, W2, b2, x_out, ld_out);
    } else {
        ar_site_kernel<false><<<dim3(4096), dim3(256), 0, stream>>>(
            z, nullptr, nullptr, W1, b1, W2, b2, x_out, ld_out);
    }
}

// Round 10
// 111.675 us; speedup vs baseline: 1.1883x; 1.1883x over previous
//
#include <hip/hip_runtime.h>
#include <math.h>

#define B_DIM 1024
#define D_DIM 512
#define H_DIM 128
#define S_DIM 511
#define PI_F 3.14159265358979323846f
#define ZSWZ_BYTES (8u * 1024u * 128u)      /* 1 MiB: z bf16, fragment-ordered */
#define NTILES_TOTAL 2296                    /* sum over s of ceil((s+1)/64) */
#define W1BF_BYTES ((size_t)NTILES_TOTAL * 16384)
#define SLOT_BYTES 49152                     /* A 32KB + B 16KB */
#define EPI_OFF 98304                        /* after 2 slots */

typedef __attribute__((ext_vector_type(8))) short short8;
typedef __attribute__((ext_vector_type(4))) float f32x4;

#define GLDS16(src, dst)                                                        \
    __builtin_amdgcn_global_load_lds(                                           \
        (const __attribute__((address_space(1))) unsigned int*)(src),           \
        (__attribute__((address_space(3))) unsigned int*)(dst), 16, 0, 0)

static __device__ __forceinline__ unsigned cvt_pk_bf16(float lo, float hi) {
    unsigned r;
    asm("v_cvt_pk_bf16_f32 %0, %1, %2" : "=v"(r) : "v"(lo), "v"(hi));
    return r;
}

// 64-wide k-tiles before site s in the packed W1bf buffer
static __device__ __forceinline__ int tiles_before(int s) {
    const int q = s >> 6, r = s & 63;
    return s + 32 * q * (q - 1) + q * r;
}

// Fragment-ordered 16KB tile (128 rows x 64 k bf16):
//   chunk(row r, k-granule g 0..7) at ((r>>4)*2+(g>>2))*1024 + (g&3)*256 + (r&15)*16
// wave frag read (rowblock R, ks): base + (R*2+ks)*1024 + l16*256 + l15*16  (contiguous 1KB)

// ---------------------------------------------------------------------------
// Pack kernel (R9, verified). z -> frag-ordered bf16 tiles [rb128 0..7][kt 0..7];
// W1 -> frag-ordered [h][k] 16KB tiles, triangular-packed, K-mask baked in.
// ---------------------------------------------------------------------------
__global__ __launch_bounds__(256) void pack_kernel(
        const float* __restrict__ z, const float* __restrict__ W1,
        unsigned char* __restrict__ z_frag, unsigned char* __restrict__ w1bf)
{
    if (blockIdx.x < 256) {
        const int gid = blockIdx.x * 256 + threadIdx.x;   // 65536 threads
        const int g   = gid & 7;
        const int row = (gid >> 3) & 1023;
        const int kt  = gid >> 13;
        const float* src = z + (size_t)row * D_DIM + kt * 64 + g * 8;
        float4 a = *(const float4*)src;
        float4 b = *(const float4*)(src + 4);
        uint4 w;
        w.x = cvt_pk_bf16(a.x, a.y);
        w.y = cvt_pk_bf16(a.z, a.w);
        w.z = cvt_pk_bf16(b.x, b.y);
        w.w = cvt_pk_bf16(b.z, b.w);
        const int r7 = row & 127;
        const int tile = (row >> 7) * 8 + kt;
        const int off = (((r7 >> 4) * 2 + (g >> 2)) << 10) + ((g & 3) << 8) + ((r7 & 15) << 4);
        *(uint4*)(z_frag + (size_t)tile * 16384 + off) = w;
        return;
    }
    const int tb = blockIdx.x - 256;          // 0..4087
    const int s  = tb >> 3;
    const int kk = tb & 7;
    if (s >= S_DIM || kk > (s >> 6)) return;
    const int k0 = kk << 6;
    const int t  = threadIdx.x;
    const int h2 = t & 63;
    const int mw = t >> 6;
    const float* __restrict__ W1s = W1 + (size_t)s * (D_DIM * H_DIM);
    unsigned char* out = w1bf + (size_t)(tiles_before(s) + kk) * 16384;
    const int h0 = h2 * 2, h1 = h2 * 2 + 1;
#pragma unroll
    for (int half = 0; half < 2; ++half) {
        const int m = mw + half * 4;
        float2 v[8];
#pragma unroll
        for (int e = 0; e < 8; ++e) {
            const int gk = k0 + m * 8 + e;
            v[e] = (gk <= s) ? *(const float2*)(W1s + (size_t)gk * H_DIM + h0)
                             : (float2){0.f, 0.f};
        }
        uint4 w0, w1;
        w0.x = cvt_pk_bf16(v[0].x, v[1].x); w0.y = cvt_pk_bf16(v[2].x, v[3].x);
        w0.z = cvt_pk_bf16(v[4].x, v[5].x); w0.w = cvt_pk_bf16(v[6].x, v[7].x);
        w1.x = cvt_pk_bf16(v[0].y, v[1].y); w1.y = cvt_pk_bf16(v[2].y, v[3].y);
        w1.z = cvt_pk_bf16(v[4].y, v[5].y); w1.w = cvt_pk_bf16(v[6].y, v[7].y);
        const int base0 = (((h0 >> 4) * 2 + (m >> 2)) << 10) + ((m & 3) << 8);
        *(uint4*)(out + base0 + ((h0 & 15) << 4)) = w0;
        *(uint4*)(out + base0 + ((h1 & 15) << 4)) = w1;
    }
}

// ---------------------------------------------------------------------------
// 8-phase-style chained kernel (PRE=true): 256 blocks x 512 thr (1/CU),
// tile 256x128, 8 waves of 64x64, BK=64, 2-slot ring. Per K-step: 4 phases
// {ds_read quadrant ∥ 2 glds -> barrier -> setprio -> 8 MFMA -> setprio ->
// barrier}; one vmcnt(0) per step (drains the 6 loads issued ~3 phases ago).
// ---------------------------------------------------------------------------
template<bool PRE>
__global__ __launch_bounds__(512, 2) void ar_site_kernel(
        const float* __restrict__ z, const unsigned char* __restrict__ z_frag,
        const unsigned char* __restrict__ w1bf,
        const float* __restrict__ W1, const float* __restrict__ b1,
        const float* __restrict__ W2, const float* __restrict__ b2,
        float* __restrict__ x_out, float* __restrict__ ld_out)
{
    __shared__ __align__(16) unsigned char lds[114688]; // 2x48KB slots + 16KB epi

    const int tid  = threadIdx.x;
    const int lane = tid & 63;
    const int wid  = tid >> 6;
    const int l15  = lane & 15;
    const int l16  = lane >> 4;

    if (PRE) {
        const int wr   = wid >> 1;              // 0..3: rows wr*64..+63
        const int wc   = wid & 1;               // 0..1: cols wc*64..+63
        const int ib   = blockIdx.x;            // 0..255
        const int c    = (((ib >> 3) & 7) << 3) | (ib & 7);  // chain 0..63
        const int bblk = ib >> 6;               // 0..3 (256-row block)
        const int brow0 = bblk * 256;

        int pf_t = 0, pf_kk = 0;
        int pf_s = 510 - c;
        int pf_base = tiles_before(pf_s);
        int step = -1;                          // so (step+1)&1 == 0 in prologue

        auto glds_two = [&](int i0) {
            if (pf_t >= 8) return;
            unsigned char* sb = lds + ((step + 1) & 1) * SLOT_BYTES;
#pragma unroll
            for (int i = i0; i < i0 + 2; ++i) {
                const int si = wid * 6 + i;     // 0..47
                if (si < 32) {
                    const unsigned char* src = z_frag
                        + (((size_t)((bblk * 2 + (si >> 4)) * 8 + pf_kk)) << 14)
                        + (si & 15) * 1024 + lane * 16;
                    GLDS16(src, sb + (si >> 4) * 16384 + (si & 15) * 1024);
                } else {
                    const unsigned char* src = w1bf
                        + (((size_t)(pf_base + pf_kk)) << 14)
                        + (si - 32) * 1024 + lane * 16;
                    GLDS16(src, sb + 32768 + (si - 32) * 1024);
                }
            }
        };
        auto pf_advance = [&]() {
            if (pf_t >= 8) return;
            ++pf_kk;
            if (pf_kk == (pf_s >> 6) + 1) {
                pf_kk = 0; ++pf_t;
                while (pf_t < 8) {
                    const int jj = pf_t * 64 + ((pf_t & 1) ? (63 - c) : c);
                    if (jj < S_DIM) { pf_s = 510 - jj; pf_base = tiles_before(pf_s); break; }
                    ++pf_t;
                }
            }
        };

#define DS_AF(mi, ks) (*(const short8*)(slotA + (wr >> 1) * 16384                 \
                        + (((((wr & 1) * 4 + (mi)) * 2 + (ks))) << 10)            \
                        + l16 * 256 + l15 * 16))
#define DS_BF(ni, ks) (*(const short8*)(slotB                                     \
                        + ((((wc * 4 + (ni)) * 2 + (ks))) << 10)                  \
                        + l16 * 256 + l15 * 16))
#define MFMA8(aa0, aa1, m0, m1, bb0, bb1, bb2, bb3)                               \
        __builtin_amdgcn_s_setprio(1);                                            \
        acc[m0][0] = __builtin_amdgcn_mfma_f32_16x16x32_bf16(aa0, bb0, acc[m0][0], 0, 0, 0); \
        acc[m0][1] = __builtin_amdgcn_mfma_f32_16x16x32_bf16(aa0, bb1, acc[m0][1], 0, 0, 0); \
        acc[m0][2] = __builtin_amdgcn_mfma_f32_16x16x32_bf16(aa0, bb2, acc[m0][2], 0, 0, 0); \
        acc[m0][3] = __builtin_amdgcn_mfma_f32_16x16x32_bf16(aa0, bb3, acc[m0][3], 0, 0, 0); \
        acc[m1][0] = __builtin_amdgcn_mfma_f32_16x16x32_bf16(aa1, bb0, acc[m1][0], 0, 0, 0); \
        acc[m1][1] = __builtin_amdgcn_mfma_f32_16x16x32_bf16(aa1, bb1, acc[m1][1], 0, 0, 0); \
        acc[m1][2] = __builtin_amdgcn_mfma_f32_16x16x32_bf16(aa1, bb2, acc[m1][2], 0, 0, 0); \
        acc[m1][3] = __builtin_amdgcn_mfma_f32_16x16x32_bf16(aa1, bb3, acc[m1][3], 0, 0, 0); \
        __builtin_amdgcn_s_setprio(0);

        // prologue: stage tile 0 into slot 0
        glds_two(0); glds_two(2); glds_two(4);
        pf_advance();
        step = 0;
        float ld_acc = 0.f;

        for (int t = 0; t < 8; ++t) {
            const int j = t * 64 + ((t & 1) ? (63 - c) : c);
            if (j >= S_DIM) continue;
            const int s   = 510 - j;
            const int nt  = (s >> 6) + 1;
            const int idx = s + 1;

            f32x4 acc[4][4];
#pragma unroll
            for (int mi = 0; mi < 4; ++mi)
#pragma unroll
                for (int ni = 0; ni < 4; ++ni)
                    acc[mi][ni] = (f32x4){0.f, 0.f, 0.f, 0.f};

            for (int kk = 0; kk < nt; ++kk) {
                asm volatile("s_waitcnt vmcnt(0)" ::: "memory");  // this slot's 6 loads
                __builtin_amdgcn_s_barrier();
                __builtin_amdgcn_sched_barrier(0);
                const unsigned char* slotA = lds + (step & 1) * SLOT_BYTES;
                const unsigned char* slotB = slotA + 32768;

                // ---- phase 0: ks0 quadrant (mi 0-1) + B ks0
                short8 a0 = DS_AF(0, 0), a1 = DS_AF(1, 0);
                short8 b0 = DS_BF(0, 0), b1 = DS_BF(1, 0), b2 = DS_BF(2, 0), b3 = DS_BF(3, 0);
                glds_two(0);
                __builtin_amdgcn_s_barrier();
                MFMA8(a0, a1, 0, 1, b0, b1, b2, b3);
                __builtin_amdgcn_s_barrier();

                // ---- phase 1: ks0 (mi 2-3), reuse b0..b3
                short8 a2 = DS_AF(2, 0), a3 = DS_AF(3, 0);
                glds_two(2);
                __builtin_amdgcn_s_barrier();
                MFMA8(a2, a3, 2, 3, b0, b1, b2, b3);
                __builtin_amdgcn_s_barrier();

                // ---- phase 2: ks1 (mi 0-1) + B ks1
                a0 = DS_AF(0, 1); a1 = DS_AF(1, 1);
                b0 = DS_BF(0, 1); b1 = DS_BF(1, 1); b2 = DS_BF(2, 1); b3 = DS_BF(3, 1);
                glds_two(4);
                __builtin_amdgcn_s_barrier();
                MFMA8(a0, a1, 0, 1, b0, b1, b2, b3);
                __builtin_amdgcn_s_barrier();

                // ---- phase 3: ks1 (mi 2-3)
                a2 = DS_AF(2, 1); a3 = DS_AF(3, 1);
                __builtin_amdgcn_s_barrier();
                MFMA8(a2, a3, 2, 3, b0, b1, b2, b3);

                pf_advance();
                ++step;
            }

            // ---- site epilogue: p = relu(acc+b1) @ W2, then NCP transform
            float b1v[4], w2a[4], w2b[4];
#pragma unroll
            for (int ni = 0; ni < 4; ++ni) {
                const int cc = wc * 64 + ni * 16 + l15;
                b1v[ni] = b1[(size_t)s * H_DIM + cc];
                const float2 w2v = *(const float2*)(W2 + ((size_t)s * H_DIM + cc) * 2);
                w2a[ni] = w2v.x;
                w2b[ni] = w2v.y;
            }
            float p0s[4][4], p1s[4][4];
#pragma unroll
            for (int mi = 0; mi < 4; ++mi)
#pragma unroll
                for (int r = 0; r < 4; ++r) {
                    float p0 = 0.f, p1 = 0.f;
#pragma unroll
                    for (int ni = 0; ni < 4; ++ni) {
                        float h = fmaxf(acc[mi][ni][r] + b1v[ni], 0.f);
                        p0 = fmaf(h, w2a[ni], p0);
                        p1 = fmaf(h, w2b[ni], p1);
                    }
                    p0s[mi][r] = p0; p1s[mi][r] = p1;
                }
#pragma unroll
            for (int mi = 0; mi < 4; ++mi)
#pragma unroll
                for (int r = 0; r < 4; ++r) {
                    p0s[mi][r] += __shfl_xor(p0s[mi][r], 1);
                    p0s[mi][r] += __shfl_xor(p0s[mi][r], 2);
                    p1s[mi][r] += __shfl_xor(p1s[mi][r], 1);
                    p1s[mi][r] += __shfl_xor(p1s[mi][r], 2);
                }
            __builtin_amdgcn_s_barrier();   // all MFMA/ds of K-loop done everywhere
            if ((lane & 3) == 0) {
                const int cw = wc * 4 + (l15 >> 2);
#pragma unroll
                for (int mi = 0; mi < 4; ++mi)
#pragma unroll
                    for (int r = 0; r < 4; ++r) {
                        const int row = wr * 64 + mi * 16 + l16 * 4 + r;  // 0..255
                        *(float2*)(lds + EPI_OFF + (row * 8 + (cw ^ (row & 7))) * 8)
                            = (float2){p0s[mi][r], p1s[mi][r]};
                    }
            }
            __syncthreads();
            if (tid < 256) {
                const int row = tid;
                float alpha = b2[(size_t)s * 2 + 0];
                float beta  = b2[(size_t)s * 2 + 1];
#pragma unroll
                for (int cw = 0; cw < 8; ++cw) {
                    const float2 v = *(const float2*)(lds + EPI_OFF + (row * 8 + (cw ^ (row & 7))) * 8);
                    alpha += v.x; beta += v.y;
                }
                const int grow = brow0 + row;
                const float phi = z[(size_t)grow * D_DIM + idx];
                const float u = tanf(0.5f * (phi - PI_F));
                const float a = expf(alpha);
                const float v = fmaf(a, u, beta);
                x_out[(size_t)grow * D_DIM + idx] = 2.0f * atanf(v) + PI_F;
                ld_acc += alpha + log1pf(u * u) - log1pf(v * v);
            }
            __syncthreads();
        }
        if (tid < 256) atomicAdd(ld_out + brow0 + tid, ld_acc);
        if (c == 0 && tid < 256)
            x_out[(size_t)(brow0 + tid) * D_DIM] = z[(size_t)(brow0 + tid) * D_DIM];
        return;
#undef DS_AF
#undef DS_BF
#undef MFMA8
    }

    // ---------------- legacy fallback: one site per block, in-kernel cvt ----
    const int wr2 = wid >> 1, wc2 = wid & 1;
    const int EPI2 = 32768;
    const int ib    = blockIdx.x;
    const int s_idx = ((ib >> 6) << 3) | (ib & 7);
    if (s_idx >= S_DIM) return;
    const int s     = S_DIM - 1 - s_idx;
    const int bblk  = (ib >> 3) & 7;
    const int brow0 = bblk * 128;
    const int K     = s + 1;
    const int idx   = s + 1;
    const float* __restrict__ W1s = W1 + (size_t)s * (D_DIM * H_DIM);

    f32x4 acc[4][4];
#pragma unroll
    for (int mi = 0; mi < 4; ++mi)
#pragma unroll
        for (int ni = 0; ni < 4; ++ni)
            acc[mi][ni] = (f32x4){0.f, 0.f, 0.f, 0.f};

    const int ntiles = (K + 63) >> 6;
    for (int kk = 0; kk < ntiles; ++kk) {
        const int k0 = kk << 6;
        const int g  = tid & 7;
        const int rb = tid >> 3;
#pragma unroll
        for (int p = 0; p < 4; ++p) {
            const int row  = p * 32 + rb;
            const int srcg = g ^ (row & 7);
            const float* zp = z + (size_t)(brow0 + row) * D_DIM + k0 + srcg * 8;
            float4 va = *(const float4*)zp;
            float4 vb = *(const float4*)(zp + 4);
            uint4 w;
            w.x = cvt_pk_bf16(va.x, va.y);
            w.y = cvt_pk_bf16(va.z, va.w);
            w.z = cvt_pk_bf16(vb.x, vb.y);
            w.w = cvt_pk_bf16(vb.z, vb.w);
            *(uint4*)(lds + row * 128 + g * 16) = w;
        }
        const int hgrp  = tid & 31;
        const int kgrp  = tid >> 5;
        const int kbase = k0 + kgrp * 8;
        const float* wp = W1s + (size_t)kbase * H_DIM + hgrp * 4;
        float4 cc[8];
#pragma unroll
        for (int jj = 0; jj < 8; ++jj) {
            float4 v = *(const float4*)(wp + (size_t)jj * H_DIM);
            const bool ok = (kbase + jj) < K;
            v.x = ok ? v.x : 0.f;  v.y = ok ? v.y : 0.f;
            v.z = ok ? v.z : 0.f;  v.w = ok ? v.w : 0.f;
            cc[jj] = v;
        }
        const float* cf = (const float*)cc;
#pragma unroll
        for (int i2 = 0; i2 < 4; ++i2) {
            const int h = hgrp * 4 + i2;
            uint4 w;
            w.x = cvt_pk_bf16(cf[0 * 4 + i2], cf[1 * 4 + i2]);
            w.y = cvt_pk_bf16(cf[2 * 4 + i2], cf[3 * 4 + i2]);
            w.z = cvt_pk_bf16(cf[4 * 4 + i2], cf[5 * 4 + i2]);
            w.w = cvt_pk_bf16(cf[6 * 4 + i2], cf[7 * 4 + i2]);
            *(uint4*)(lds + 16384 + h * 128 + ((kgrp * 16) ^ ((h & 7) << 4))) = w;
        }
        __syncthreads();
#pragma unroll
        for (int ks = 0; ks < 2; ++ks) {
            const int kb = ks * 64 + l16 * 16;
            short8 af[4], bfr[4];
#pragma unroll
            for (int mi = 0; mi < 4; ++mi) {
                const int r = wr2 * 64 + mi * 16 + l15;
                af[mi] = *(const short8*)(lds + r * 128 + (kb ^ ((r & 7) << 4)));
            }
#pragma unroll
            for (int ni = 0; ni < 4; ++ni) {
                const int h = wc2 * 64 + ni * 16 + l15;
                bfr[ni] = *(const short8*)(lds + 16384 + h * 128 + (kb ^ ((h & 7) << 4)));
            }
#pragma unroll
            for (int mi = 0; mi < 4; ++mi)
#pragma unroll
                for (int ni = 0; ni < 4; ++ni)
                    acc[mi][ni] = __builtin_amdgcn_mfma_f32_16x16x32_bf16(
                        af[mi], bfr[ni], acc[mi][ni], 0, 0, 0);
        }
        __syncthreads();
    }

    float b1v[4], w2a[4], w2b[4];
#pragma unroll
    for (int ni = 0; ni < 4; ++ni) {
        const int cc2 = wc2 * 64 + ni * 16 + l15;
        b1v[ni] = b1[(size_t)s * H_DIM + cc2];
        const float* w2p = W2 + ((size_t)s * H_DIM + cc2) * 2;
        w2a[ni] = w2p[0];
        w2b[ni] = w2p[1];
    }
    float p0s[4][4], p1s[4][4];
#pragma unroll
    for (int mi = 0; mi < 4; ++mi)
#pragma unroll
        for (int r = 0; r < 4; ++r) {
            float p0 = 0.f, p1 = 0.f;
#pragma unroll
            for (int ni = 0; ni < 4; ++ni) {
                float h = fmaxf(acc[mi][ni][r] + b1v[ni], 0.f);
                p0 = fmaf(h, w2a[ni], p0);
                p1 = fmaf(h, w2b[ni], p1);
            }
            p0s[mi][r] = p0; p1s[mi][r] = p1;
        }
#pragma unroll
    for (int mi = 0; mi < 4; ++mi)
#pragma unroll
        for (int r = 0; r < 4; ++r) {
            p0s[mi][r] += __shfl_xor(p0s[mi][r], 1);
            p0s[mi][r] += __shfl_xor(p0s[mi][r], 2);
            p1s[mi][r] += __shfl_xor(p1s[mi][r], 1);
            p1s[mi][r] += __shfl_xor(p1s[mi][r], 2);
        }
    if ((lane & 3) == 0) {
        const int cw = wc2 * 4 + (l15 >> 2);
#pragma unroll
        for (int mi = 0; mi < 4; ++mi)
#pragma unroll
            for (int r = 0; r < 4; ++r) {
                const int row = wr2 * 64 + mi * 16 + l16 * 4 + r;
                *(float2*)(lds + EPI2 + (row * 8 + (cw ^ (row & 7))) * 8)
                    = (float2){p0s[mi][r], p1s[mi][r]};
            }
    }
    __syncthreads();
    if (tid < 128) {
        const int row = tid;
        float alpha = b2[(size_t)s * 2 + 0];
        float beta  = b2[(size_t)s * 2 + 1];
#pragma unroll
        for (int cw = 0; cw < 8; ++cw) {
            const float2 v = *(const float2*)(lds + EPI2 + (row * 8 + (cw ^ (row & 7))) * 8);
            alpha += v.x; beta += v.y;
        }
        const int grow = brow0 + row;
        const float phi = z[(size_t)grow * D_DIM + idx];
        const float u = tanf(0.5f * (phi - PI_F));
        const float a = expf(alpha);
        const float v = fmaf(a, u, beta);
        x_out[(size_t)grow * D_DIM + idx] = 2.0f * atanf(v) + PI_F;
        atomicAdd(ld_out + grow, alpha + log1pf(u * u) - log1pf(v * v));
        if (s_idx == 0)
            x_out[(size_t)grow * D_DIM] = z[(size_t)grow * D_DIM];
    }
}

extern "C" void kernel_launch(void* const* d_in, const int* in_sizes, int n_in,
                              void* d_out, int out_size, void* d_ws, size_t ws_size,
                              hipStream_t stream) {
    const float* z  = (const float*)d_in[0];
    const float* W1 = (const float*)d_in[1];
    const float* b1 = (const float*)d_in[2];
    const float* W2 = (const float*)d_in[3];
    const float* b2 = (const float*)d_in[4];
    float* x_out  = (float*)d_out;
    float* ld_out = x_out + (size_t)B_DIM * D_DIM;

    unsigned char* z_frag = (unsigned char*)d_ws;
    unsigned char* w1bf   = z_frag + ZSWZ_BYTES;
    const size_t need = ZSWZ_BYTES + W1BF_BYTES;

    hipMemsetAsync(ld_out, 0, B_DIM * sizeof(float), stream);
    if (ws_size >= need) {
        pack_kernel<<<dim3(256 + 4088), dim3(256), 0, stream>>>(z, W1, z_frag, w1bf);
        ar_site_kernel<true><<<dim3(256), dim3(512), 0, stream>>>(
            z, z_frag, w1bf, W1, b1, W2, b2, x_out, ld_out);
    } else {
        ar_site_kernel<false><<<dim3(4096), dim3(256), 0, stream>>>(
            z, nullptr, nullptr, W1, b1, W2, b2, x_out, ld_out);
    }
}